// Round 1
// 321.749 us; speedup vs baseline: 1.0162x; 1.0162x over previous
//
#include <hip/hip_runtime.h>
#include <cstdint>
#include <cstddef>

#define T_SEQ 4096
#define BATCH 2
#define HIDDEN 1024
#define NHEAD 8
#define DKV 128
#define BT (BATCH * T_SEQ)   // 8192
#define NCH 64               // chunks per batch
#define CHUNK_L 64
#define QSCALE 0.08838834764831845f
#define SCALE_P 1024.0f
#define SCALE_O 8192.0f
#define OEPS 0.7071067811865476f

typedef _Float16 half8 __attribute__((ext_vector_type(8)));
typedef float floatx4 __attribute__((ext_vector_type(4)));

union HBits { _Float16 h; unsigned short u; };

// ---------------------------------------------------------------------------
// fp32 -> fp16 cast, 8 elements/thread
// ---------------------------------------------------------------------------
__global__ void cast_f32_f16(const float* __restrict__ X, _Float16* __restrict__ Y, int n8)
{
    int idx = blockIdx.x * 256 + threadIdx.x;
    if (idx < n8) {
        float4 a = ((const float4*)X)[idx * 2];
        float4 b = ((const float4*)X)[idx * 2 + 1];
        half8 h = { (_Float16)a.x, (_Float16)a.y, (_Float16)a.z, (_Float16)a.w,
                    (_Float16)b.x, (_Float16)b.y, (_Float16)b.z, (_Float16)b.w };
        *(half8*)&Y[idx * 8] = h;
    }
}

// 8 weight tensors in one launch; blockIdx.y selects.
__global__ void cast8_f32_f16(const float* __restrict__ s0, const float* __restrict__ s1,
                              const float* __restrict__ s2, const float* __restrict__ s3,
                              const float* __restrict__ s4, const float* __restrict__ s5,
                              const float* __restrict__ s6, const float* __restrict__ s7,
                              _Float16* __restrict__ d0, _Float16* __restrict__ d1,
                              _Float16* __restrict__ d2, _Float16* __restrict__ d3,
                              _Float16* __restrict__ d4, _Float16* __restrict__ d5,
                              _Float16* __restrict__ d6, _Float16* __restrict__ d7,
                              int nbig, int nsmall)
{
    int sel = blockIdx.y;
    const float* src; _Float16* dst; int n8;
    switch (sel) {
        case 0: src = s0; dst = d0; n8 = nbig; break;
        case 1: src = s1; dst = d1; n8 = nbig; break;
        case 2: src = s2; dst = d2; n8 = nbig; break;
        case 3: src = s3; dst = d3; n8 = nbig; break;
        case 4: src = s4; dst = d4; n8 = nsmall; break;
        case 5: src = s5; dst = d5; n8 = nsmall; break;
        case 6: src = s6; dst = d6; n8 = nsmall; break;
        default: src = s7; dst = d7; n8 = nsmall; break;
    }
    int idx = blockIdx.x * 256 + threadIdx.x;
    if (idx < n8) {
        float4 u = ((const float4*)src)[idx * 2];
        float4 v = ((const float4*)src)[idx * 2 + 1];
        half8 h = { (_Float16)u.x, (_Float16)u.y, (_Float16)u.z, (_Float16)u.w,
                    (_Float16)v.x, (_Float16)v.y, (_Float16)v.z, (_Float16)v.w };
        *(half8*)&dst[idx * 8] = h;
    }
}

// ---------------------------------------------------------------------------
// GEMM (NT) fp16 MFMA, fp16 out: 256x256 tile, BK=64, 8 waves, 8-phase
// counted-vmcnt schedule (T3+T4+T5).  LDS chunk-XOR swizzle identical to the
// proven 128^2 kernel (0 bank conflicts measured).
//
// Per K-tile (4 phases, 2 barriers each):
//   ph0: ds a(rows 0-63 of wave half, both kslices)=8 + b(j0,j1)=4; stage A[t+1] q0,q1
//   ph1: ds b(j2,j3)=4;                                            stage A[t+1] q2,q3
//   ph2: ds a(rows 64-127)=8;                                      stage W[t+2] q0,q1
//   ph3: (no ds);                                                  stage W[t+2] q2,q3
//        end-of-tile wait: vmcnt(4) (W[t+2] stays in flight) / vmcnt(0) at t=NT-2.
// Race audit: A[t+1] -> buffer idle since tile t-1 ph2; W[t+2] -> current W
// buffer, fully read by ph1's lgkmcnt(0)+barrier before the ph2 issue.
// ---------------------------------------------------------------------------
#define TILEH 16384   // halfs in one 256x64 tile

__global__ __launch_bounds__(512, 2) void gemm256_nt_f16_h16(
    const _Float16* __restrict__ A, const _Float16* __restrict__ W,
    _Float16* __restrict__ C, int M, int N, int K)
{
    __shared__ _Float16 As[2 * TILEH];
    __shared__ _Float16 Ws[2 * TILEH];
    const int bm = blockIdx.y * 256;
    const int bn = blockIdx.x * 256;
    const int tid = threadIdx.x;
    const int w = tid >> 6;          // wave 0..7 (uniform per wave)
    const int l = tid & 63;
    const int lane16 = l & 15;
    const int quad = l >> 4;
    const int wr = w >> 2;           // 0..1 : 128-row half
    const int wc = w & 3;            // 0..3 : 64-col slice
    const int NT = K >> 6;

    // staging: thread covers row q*64 + (tid>>3), 16B chunk (tid&7)^(row&7)
    const int srow = tid >> 3;
    const int sch = (tid & 7) ^ (srow & 7);

#define STAGE(src, baseRow, k0, q, dst)                                           \
    __builtin_amdgcn_global_load_lds(                                             \
        (const __attribute__((address_space(1))) void*)((src) +                   \
            (size_t)((baseRow) + (q) * 64 + srow) * K + (k0) + sch * 8),          \
        (__attribute__((address_space(3))) void*)((dst) + (q) * 4096 + w * 512),  \
        16, 0, 0)

    floatx4 acc[8][4];
#pragma unroll
    for (int i = 0; i < 8; ++i)
#pragma unroll
        for (int j = 0; j < 4; ++j)
            acc[i][j] = (floatx4){0.f, 0.f, 0.f, 0.f};

    // ---- prologue: W[0](4) A[0](4) W[1](4); wait oldest 8; barrier ----
    {
#pragma unroll
        for (int q = 0; q < 4; ++q) STAGE(W, bn, 0, q, Ws);
#pragma unroll
        for (int q = 0; q < 4; ++q) STAGE(A, bm, 0, q, As);
        if (NT > 1) {
#pragma unroll
            for (int q = 0; q < 4; ++q) STAGE(W, bn, 64, q, Ws + TILEH);
            asm volatile("s_waitcnt vmcnt(4)" ::: "memory");
        } else {
            asm volatile("s_waitcnt vmcnt(0)" ::: "memory");
        }
        __builtin_amdgcn_s_barrier();
        asm volatile("" ::: "memory");
    }

    for (int t = 0; t < NT; ++t) {
        const int bsel = t & 1;
        const _Float16* Asb = As + bsel * TILEH;
        const _Float16* Wsb = Ws + bsel * TILEH;
        _Float16* AsN = As + (bsel ^ 1) * TILEH;  // A[t+1] dest
        _Float16* WsN = Ws + bsel * TILEH;        // W[t+2] dest (current buf)
        const int kA = (t + 1) << 6;
        const int kW = (t + 2) << 6;
        const bool doA = (t + 1) < NT;
        const bool doW = (t + 2) < NT;

        half8 a[4][2], b[4][2];

        // ================= phase 0 =================
#pragma unroll
        for (int i = 0; i < 4; ++i)
#pragma unroll
            for (int s = 0; s < 2; ++s) {
                int row = wr * 128 + i * 16 + lane16;
                a[i][s] = *(const half8*)&Asb[row * 64 + (((s * 4 + quad) ^ (row & 7)) << 3)];
            }
#pragma unroll
        for (int j = 0; j < 2; ++j)
#pragma unroll
            for (int s = 0; s < 2; ++s) {
                int row = wc * 64 + j * 16 + lane16;
                b[j][s] = *(const half8*)&Wsb[row * 64 + (((s * 4 + quad) ^ (row & 7)) << 3)];
            }
        if (doA) { STAGE(A, bm, kA, 0, AsN); STAGE(A, bm, kA, 1, AsN); }
        asm volatile("s_waitcnt lgkmcnt(8)" ::: "memory");
        __builtin_amdgcn_s_barrier();
        asm volatile("s_waitcnt lgkmcnt(0)" ::: "memory");
        __builtin_amdgcn_s_setprio(1);
#pragma unroll
        for (int s = 0; s < 2; ++s)
#pragma unroll
            for (int i = 0; i < 4; ++i)
#pragma unroll
                for (int j = 0; j < 2; ++j)
                    acc[i][j] = __builtin_amdgcn_mfma_f32_16x16x32_f16(a[i][s], b[j][s], acc[i][j], 0, 0, 0);
        __builtin_amdgcn_s_setprio(0);
        __builtin_amdgcn_s_barrier();

        // ================= phase 1 =================
#pragma unroll
        for (int j = 2; j < 4; ++j)
#pragma unroll
            for (int s = 0; s < 2; ++s) {
                int row = wc * 64 + j * 16 + lane16;
                b[j][s] = *(const half8*)&Wsb[row * 64 + (((s * 4 + quad) ^ (row & 7)) << 3)];
            }
        if (doA) { STAGE(A, bm, kA, 2, AsN); STAGE(A, bm, kA, 3, AsN); }
        __builtin_amdgcn_s_barrier();
        asm volatile("s_waitcnt lgkmcnt(0)" ::: "memory");
        __builtin_amdgcn_s_setprio(1);
#pragma unroll
        for (int s = 0; s < 2; ++s)
#pragma unroll
            for (int i = 0; i < 4; ++i)
#pragma unroll
                for (int j = 2; j < 4; ++j)
                    acc[i][j] = __builtin_amdgcn_mfma_f32_16x16x32_f16(a[i][s], b[j][s], acc[i][j], 0, 0, 0);
        __builtin_amdgcn_s_setprio(0);
        __builtin_amdgcn_s_barrier();

        // ================= phase 2 =================
#pragma unroll
        for (int i = 0; i < 4; ++i)
#pragma unroll
            for (int s = 0; s < 2; ++s) {
                int row = wr * 128 + 64 + i * 16 + lane16;
                a[i][s] = *(const half8*)&Asb[row * 64 + (((s * 4 + quad) ^ (row & 7)) << 3)];
            }
        if (doW) { STAGE(W, bn, kW, 0, WsN); STAGE(W, bn, kW, 1, WsN); }
        __builtin_amdgcn_s_barrier();
        asm volatile("s_waitcnt lgkmcnt(0)" ::: "memory");
        __builtin_amdgcn_s_setprio(1);
#pragma unroll
        for (int s = 0; s < 2; ++s)
#pragma unroll
            for (int i = 0; i < 4; ++i)
#pragma unroll
                for (int j = 0; j < 2; ++j)
                    acc[4 + i][j] = __builtin_amdgcn_mfma_f32_16x16x32_f16(a[i][s], b[j][s], acc[4 + i][j], 0, 0, 0);
        __builtin_amdgcn_s_setprio(0);
        __builtin_amdgcn_s_barrier();

        // ================= phase 3 =================
        if (doW) { STAGE(W, bn, kW, 2, WsN); STAGE(W, bn, kW, 3, WsN); }
        __builtin_amdgcn_s_barrier();
        __builtin_amdgcn_s_setprio(1);
#pragma unroll
        for (int s = 0; s < 2; ++s)
#pragma unroll
            for (int i = 0; i < 4; ++i)
#pragma unroll
                for (int j = 2; j < 4; ++j)
                    acc[4 + i][j] = __builtin_amdgcn_mfma_f32_16x16x32_f16(a[i][s], b[j][s], acc[4 + i][j], 0, 0, 0);
        __builtin_amdgcn_s_setprio(0);
        if (doW)      asm volatile("s_waitcnt vmcnt(4)" ::: "memory");
        else if (doA) asm volatile("s_waitcnt vmcnt(0)" ::: "memory");
        __builtin_amdgcn_s_barrier();
        asm volatile("" ::: "memory");
    }
#undef STAGE

    // ---- epilogue: C write (fp16) ----
#pragma unroll
    for (int i = 0; i < 8; ++i)
#pragma unroll
        for (int j = 0; j < 4; ++j)
#pragma unroll
            for (int r = 0; r < 4; ++r)
                C[(size_t)(bm + wr * 128 + i * 16 + quad * 4 + r) * N +
                  bn + wc * 64 + j * 16 + lane16] = (_Float16)acc[i][j][r];
}

// ---------------------------------------------------------------------------
// 128x128 BK=64 structure, fp32 out with scale (final projection; undoes
// SCALE_O).  Grid here is only 512 blocks with N=1024 -> the 256^2 8-phase
// kernel would drop to 128 blocks (half the CUs idle), so keep this one.
// ---------------------------------------------------------------------------
__global__ __launch_bounds__(256) void gemm_nt_f16_f32(const _Float16* __restrict__ A,
                                                       const _Float16* __restrict__ W,
                                                       float* __restrict__ C,
                                                       int M, int N, int K, float scale)
{
    __shared__ _Float16 As[128 * 64];
    __shared__ _Float16 Ws[128 * 64];
    const int bm = blockIdx.y * 128;
    const int bn = blockIdx.x * 128;
    const int tid = threadIdx.x;
    const int w = tid >> 6;
    const int l = tid & 63;
    const int wm = (w >> 1) * 64;
    const int wn = (w & 1) * 64;
    const int lane16 = l & 15;
    const int quad = l >> 4;
    const int srow = w * 8 + (l >> 3);
    const int skh = ((l & 7) ^ (l >> 3)) * 8;
    const int rsw = lane16 & 7;

    floatx4 acc[4][4];
#pragma unroll
    for (int i = 0; i < 4; ++i)
#pragma unroll
        for (int j = 0; j < 4; ++j)
            acc[i][j] = (floatx4){0.f, 0.f, 0.f, 0.f};

    for (int k0 = 0; k0 < K; k0 += 64) {
#pragma unroll
        for (int c = 0; c < 4; ++c) {
            int row = c * 32 + srow;
            const _Float16* ga = A + (size_t)(bm + row) * K + k0 + skh;
            const _Float16* gw = W + (size_t)(bn + row) * K + k0 + skh;
            __builtin_amdgcn_global_load_lds(
                (const __attribute__((address_space(1))) void*)ga,
                (__attribute__((address_space(3))) void*)(As + c * 2048 + w * 512), 16, 0, 0);
            __builtin_amdgcn_global_load_lds(
                (const __attribute__((address_space(1))) void*)gw,
                (__attribute__((address_space(3))) void*)(Ws + c * 2048 + w * 512), 16, 0, 0);
        }
        __syncthreads();

#pragma unroll
        for (int s = 0; s < 2; ++s) {
            const int pc = (((s * 4 + quad) ^ rsw)) * 8;
            half8 a[4], b[4];
#pragma unroll
            for (int i = 0; i < 4; ++i) {
                a[i] = *(const half8*)&As[(wm + i * 16 + lane16) * 64 + pc];
                b[i] = *(const half8*)&Ws[(wn + i * 16 + lane16) * 64 + pc];
            }
#pragma unroll
            for (int i = 0; i < 4; ++i)
#pragma unroll
                for (int j = 0; j < 4; ++j)
                    acc[i][j] = __builtin_amdgcn_mfma_f32_16x16x32_f16(a[i], b[j], acc[i][j], 0, 0, 0);
        }
        __syncthreads();
    }
#pragma unroll
    for (int i = 0; i < 4; ++i)
#pragma unroll
        for (int j = 0; j < 4; ++j)
#pragma unroll
            for (int r = 0; r < 4; ++r)
                C[(size_t)(bm + wm + i * 16 + quad * 4 + r) * N + bn + wn + j * 16 + lane16] =
                    acc[i][j][r] * scale;
}

// ---------------------------------------------------------------------------
// Conv + SiLU for V, writing TRANSPOSED: vT[b*1024 + d][t]  (fp16).
// grid.x = 2048 = 64 ttiles * 16 dtiles * 2 batch.
// ---------------------------------------------------------------------------
__global__ __launch_bounds__(256) void conv_silu_T(const _Float16* __restrict__ X, int ldx,
                                                   const float* __restrict__ Wc,
                                                   _Float16* __restrict__ VT)
{
    __shared__ _Float16 xs[67 * 64];
    const int bx = blockIdx.x;
    const int t0 = (bx & 63) * 64;
    const int dt = ((bx >> 6) & 15) * 64;
    const int z = bx >> 10;
    const int tid = threadIdx.x;

#pragma unroll
    for (int i = 0; i < 3; ++i) {
        int p = tid + 256 * i;
        if (p < 536) {
            int row = p >> 3, d8 = (p & 7) * 8;
            int t = t0 - 3 + row;
            half8 v;
            if (t >= 0)
                v = *(const half8*)&X[((size_t)z * T_SEQ + t) * ldx + dt + d8];
            else
                v = (half8){0, 0, 0, 0, 0, 0, 0, 0};
            *(half8*)&xs[row * 64 + d8] = v;
        }
    }
    __syncthreads();

    const int d = tid & 63;
    const int dg = dt + d;
    float4 w = *(const float4*)&Wc[dg * 4];
#pragma unroll
    for (int u = 0; u < 2; ++u) {
        int tg = (tid >> 6) + u * 4;
        half8 o;
#pragma unroll
        for (int s = 0; s < 8; ++s) {
            int base = (tg * 8 + s + 3) * 64 + d;
            float acc = (float)xs[base] * w.w
                      + (float)xs[base - 64] * w.z
                      + (float)xs[base - 128] * w.y
                      + (float)xs[base - 192] * w.x;
            o[s] = (_Float16)(acc / (1.f + __expf(-acc)));
        }
        *(half8*)&VT[((size_t)z * HIDDEN + dg) * T_SEQ + t0 + tg * 8] = o;
    }
}

// ---------------------------------------------------------------------------
// FUSED conv+SiLU + feature map (q/k via blockIdx.z), v2.
// ---------------------------------------------------------------------------
#define XIN_LD 136   // 67 rows x 136 halfs
__global__ __launch_bounds__(256) void convfm(const _Float16* __restrict__ QKV, int ldx,
                                              const float* __restrict__ Wcq,
                                              const float* __restrict__ Wck,
                                              const _Float16* __restrict__ Wfm,  // 4x16384
                                              const float* __restrict__ Bq1,
                                              const float* __restrict__ Bq2,
                                              const float* __restrict__ Bk1,
                                              const float* __restrict__ Bk2,
                                              _Float16* __restrict__ OUTq,
                                              _Float16* __restrict__ OUTk)
{
    const int sel = blockIdx.z;
    const float* Wc = sel ? Wck : Wcq;
    const _Float16* W1h = Wfm + (sel ? 2 * 16384 : 0);
    const _Float16* W2h = Wfm + (sel ? 3 * 16384 : 16384);
    const float* B1 = sel ? Bk1 : Bq1;
    const float* B2 = sel ? Bk2 : Bq2;
    _Float16* OUT = sel ? OUTk : OUTq;

    __shared__ _Float16 xin[67 * XIN_LD];    // input window (t0-3 .. t0+63) x 128
    __shared__ _Float16 xs[4 * 64 * 32];     // conv output, MFMA staging layout
    const int t0 = blockIdx.x * 64;
    const int h = blockIdx.y;
    const int tid = threadIdx.x;
    const int w = tid >> 6;
    const int l = tid & 63;
    const int lane16 = l & 15;
    const int quad = l >> 4;
    const bool batch_start = (t0 & (T_SEQ - 1)) == 0;

    // ---- stage input window: 67 rows x 16 col-groups = 1072 half8 ----
    for (int p = tid; p < 67 * 16; p += 256) {
        int row = p >> 4, cg = p & 15;
        half8 v;
        if (batch_start && row < 3)
            v = (half8){0, 0, 0, 0, 0, 0, 0, 0};
        else
            v = *(const half8*)&QKV[(size_t)(t0 - 3 + row) * ldx + sel * HIDDEN + h * DKV + cg * 8];
        *(half8*)&xin[row * XIN_LD + cg * 8] = v;
    }
    __syncthreads();

    // ---- conv + silu: thread owns 8 channels (d-oct) x 4 rows ----
    {
        const int doct = tid & 15;       // d0 = doct*8
        const int d0 = doct * 8;
        const int rq = (tid >> 4) * 4;   // rows rq..rq+3
        const int u = doct >> 2;         // kstep slab in xs
        const int col = d0 & 31;

        float w0[8], w1[8], w2[8], w3[8];
#pragma unroll
        for (int e = 0; e < 8; ++e) {
            float4 wv = *(const float4*)&Wc[(h * DKV + d0 + e) * 4];
            w0[e] = wv.x; w1[e] = wv.y; w2[e] = wv.z; w3[e] = wv.w;
        }

#pragma unroll
        for (int rr = 0; rr < 4; ++rr) {
            const int row = rq + rr;
            half8 x3 = *(const half8*)&xin[(row + 0) * XIN_LD + d0];
            half8 x2 = *(const half8*)&xin[(row + 1) * XIN_LD + d0];
            half8 x1 = *(const half8*)&xin[(row + 2) * XIN_LD + d0];
            half8 x0 = *(const half8*)&xin[(row + 3) * XIN_LD + d0];
            half8 o;
#pragma unroll
            for (int e = 0; e < 8; ++e) {
                float acc = fmaf((float)x0[e], w3[e],
                            fmaf((float)x1[e], w2[e],
                            fmaf((float)x2[e], w1[e], (float)x3[e] * w0[e])));
                o[e] = (_Float16)(acc / (1.f + __expf(-acc)));
            }
            *(half8*)&xs[u * 2048 + row * 32 + col] = o;
        }
    }
    __syncthreads();

    // ---- dual GEMM + hadamard ----
    floatx4 acc1[4][2], acc2[4][2];
#pragma unroll
    for (int i = 0; i < 4; ++i)
#pragma unroll
        for (int j = 0; j < 2; ++j) {
            acc1[i][j] = (floatx4){0.f, 0.f, 0.f, 0.f};
            acc2[i][j] = (floatx4){0.f, 0.f, 0.f, 0.f};
        }

#pragma unroll
    for (int s = 0; s < 4; ++s) {
        half8 a[4];
#pragma unroll
        for (int mt = 0; mt < 4; ++mt)
            a[mt] = *(const half8*)&xs[s * 2048 + (mt * 16 + lane16) * 32 + quad * 8];
#pragma unroll
        for (int nt = 0; nt < 2; ++nt) {
            int e = w * 32 + nt * 16 + lane16;
            half8 b1 = *(const half8*)&W1h[(size_t)e * DKV + s * 32 + quad * 8];
            half8 b2 = *(const half8*)&W2h[(size_t)e * DKV + s * 32 + quad * 8];
#pragma unroll
            for (int mt = 0; mt < 4; ++mt) {
                acc1[mt][nt] = __builtin_amdgcn_mfma_f32_16x16x32_f16(a[mt], b1, acc1[mt][nt], 0, 0, 0);
                acc2[mt][nt] = __builtin_amdgcn_mfma_f32_16x16x32_f16(a[mt], b2, acc2[mt][nt], 0, 0, 0);
            }
        }
    }

#pragma unroll
    for (int nt = 0; nt < 2; ++nt) {
        int e = w * 32 + nt * 16 + lane16;
        float b1v = B1[e], b2v = B2[e];
#pragma unroll
        for (int mt = 0; mt < 4; ++mt)
#pragma unroll
            for (int r = 0; r < 4; ++r) {
                float o = (acc1[mt][nt][r] + b1v) * (acc2[mt][nt][r] + b2v);
                OUT[(size_t)(t0 + mt * 16 + quad * 4 + r) * HIDDEN + h * DKV + e] = (_Float16)o;
            }
    }
}

// ---------------------------------------------------------------------------
// Per-chunk S^T[dv][dk] = sum_j V[j][dv] K[j][dk], MFMA. fp16 out.
// ---------------------------------------------------------------------------
__global__ __launch_bounds__(256) void ktv_mfma(const _Float16* __restrict__ Kf,
                                                const _Float16* __restrict__ VT,
                                                _Float16* __restrict__ G16)
{
    __shared__ _Float16 kt[128 * 72];
    const int c = blockIdx.x;
    const int bh = blockIdx.y;
    const int b = bh >> 3, h = bh & 7;
    const int tid = threadIdx.x;
    const int w = tid >> 6;
    const int l = tid & 63;
    const int lane16 = l & 15;
    const int quad = l >> 4;
    const size_t rowbase = (size_t)b * T_SEQ + (size_t)c * CHUNK_L;

    {
        const int dk0 = (tid >> 4) * 8;
        const int jb = (tid & 15) * 4;
        half8 r0 = *(const half8*)&Kf[(rowbase + jb + 0) * HIDDEN + h * DKV + dk0];
        half8 r1 = *(const half8*)&Kf[(rowbase + jb + 1) * HIDDEN + h * DKV + dk0];
        half8 r2 = *(const half8*)&Kf[(rowbase + jb + 2) * HIDDEN + h * DKV + dk0];
        half8 r3 = *(const half8*)&Kf[(rowbase + jb + 3) * HIDDEN + h * DKV + dk0];
#pragma unroll
        for (int dk = 0; dk < 8; ++dk) {
            HBits a0, a1, a2, a3;
            a0.h = r0[dk]; a1.h = r1[dk]; a2.h = r2[dk]; a3.h = r3[dk];
            unsigned int lo = ((unsigned int)a1.u << 16) | a0.u;
            unsigned int hi = ((unsigned int)a3.u << 16) | a2.u;
            *(unsigned int*)&kt[(dk0 + dk) * 72 + jb] = lo;
            *(unsigned int*)&kt[(dk0 + dk) * 72 + jb + 2] = hi;
        }
    }
    __syncthreads();

    const int m0 = (w >> 1) * 64;
    const int n0 = (w & 1) * 64;
    floatx4 acc[4][4];
#pragma unroll
    for (int i = 0; i < 4; ++i)
#pragma unroll
        for (int j = 0; j < 4; ++j)
            acc[i][j] = (floatx4){0.f, 0.f, 0.f, 0.f};

#pragma unroll
    for (int s = 0; s < 2; ++s) {
        half8 a[4], bb[4];
#pragma unroll
        for (int mt = 0; mt < 4; ++mt) {
            int dv = m0 + mt * 16 + lane16;
            a[mt] = *(const half8*)&VT[((size_t)bh * DKV + dv) * T_SEQ + c * CHUNK_L + s * 32 + quad * 8];
        }
#pragma unroll
        for (int nt = 0; nt < 4; ++nt)
            bb[nt] = *(const half8*)&kt[(n0 + nt * 16 + lane16) * 72 + s * 32 + quad * 8];
#pragma unroll
        for (int mt = 0; mt < 4; ++mt)
#pragma unroll
            for (int nt = 0; nt < 4; ++nt)
                acc[mt][nt] = __builtin_amdgcn_mfma_f32_16x16x32_f16(a[mt], bb[nt], acc[mt][nt], 0, 0, 0);
    }

    _Float16* Gp = G16 + ((size_t)bh * NCH + c) * (DKV * DKV);
#pragma unroll
    for (int mt = 0; mt < 4; ++mt)
#pragma unroll
        for (int nt = 0; nt < 4; ++nt)
#pragma unroll
            for (int r = 0; r < 4; ++r)
                Gp[(size_t)(m0 + mt * 16 + quad * 4 + r) * DKV + n0 + nt * 16 + lane16] =
                    (_Float16)acc[mt][nt][r];
}

// ---------------------------------------------------------------------------
// Exclusive prefix over chunks; fp32 running sum; Gh fp16 (scaled SCALE_P).
// ---------------------------------------------------------------------------
__global__ void prefix_kernel(const _Float16* __restrict__ G16, _Float16* __restrict__ Gh)
{
    int idx = blockIdx.x * 256 + threadIdx.x;   // 16 * 16384
    int bh = idx >> 14;
    int e = idx & 16383;
    const _Float16* p = G16 + (size_t)bh * NCH * 16384 + e;
    _Float16* q = Gh + (size_t)bh * NCH * 16384 + e;
    float run = 0.f;
#pragma unroll
    for (int c = 0; c < NCH; ++c) {
        q[(size_t)c * 16384] = (_Float16)(run * SCALE_P);
        run += (float)p[(size_t)c * 16384];
    }
}

// ---------------------------------------------------------------------------
// Attention per chunk, MFMA.
// ---------------------------------------------------------------------------
#define PSLD 40
__global__ __launch_bounds__(256) void attn_mfma(const _Float16* __restrict__ Qf,
                                                 const _Float16* __restrict__ Kf,
                                                 const _Float16* __restrict__ VT,
                                                 const _Float16* __restrict__ Gh,
                                                 _Float16* __restrict__ O)
{
    __shared__ _Float16 ps[2 * 64 * PSLD];
    const int c = blockIdx.x;
    const int bh = blockIdx.y;
    const int b = bh >> 3, h = bh & 7;
    const int tid = threadIdx.x;
    const int w = tid >> 6;
    const int l = tid & 63;
    const int lane16 = l & 15;
    const int quad = l >> 4;
    const size_t rowbase = (size_t)b * T_SEQ + (size_t)c * CHUNK_L;

    {
        const int m0 = (w >> 1) * 32;
        const int n0 = (w & 1) * 32;
        floatx4 aq[2][2];
#pragma unroll
        for (int i = 0; i < 2; ++i)
#pragma unroll
            for (int j = 0; j < 2; ++j)
                aq[i][j] = (floatx4){0.f, 0.f, 0.f, 0.f};
#pragma unroll
        for (int s = 0; s < 4; ++s) {
            half8 a[2], bb[2];
#pragma unroll
            for (int mt = 0; mt < 2; ++mt)
                a[mt] = *(const half8*)&Qf[(rowbase + m0 + mt * 16 + lane16) * HIDDEN +
                                           h * DKV + s * 32 + quad * 8];
#pragma unroll
            for (int nt = 0; nt < 2; ++nt)
                bb[nt] = *(const half8*)&Kf[(rowbase + n0 + nt * 16 + lane16) * HIDDEN +
                                            h * DKV + s * 32 + quad * 8];
#pragma unroll
            for (int mt = 0; mt < 2; ++mt)
#pragma unroll
                for (int nt = 0; nt < 2; ++nt)
                    aq[mt][nt] = __builtin_amdgcn_mfma_f32_16x16x32_f16(a[mt], bb[nt], aq[mt][nt], 0, 0, 0);
        }
#pragma unroll
        for (int mt = 0; mt < 2; ++mt)
#pragma unroll
            for (int nt = 0; nt < 2; ++nt) {
                int j = n0 + nt * 16 + lane16;
#pragma unroll
                for (int r = 0; r < 4; ++r) {
                    int i = m0 + mt * 16 + quad * 4 + r;
                    float v = (j <= i) ? aq[mt][nt][r] * SCALE_P : 0.f;
                    ps[(j >> 5) * 64 * PSLD + i * PSLD + (j & 31)] = (_Float16)v;
                }
            }
    }
    __syncthreads();

    const int n0o = w * 32;
    floatx4 accO[4][2];
#pragma unroll
    for (int i = 0; i < 4; ++i)
#pragma unroll
        for (int j = 0; j < 2; ++j)
            accO[i][j] = (floatx4){0.f, 0.f, 0.f, 0.f};

#pragma unroll
    for (int s = 0; s < 2; ++s) {
        half8 a[4], bb[2];
#pragma unroll
        for (int mt = 0; mt < 4; ++mt)
            a[mt] = *(const half8*)&ps[s * 64 * PSLD + (mt * 16 + lane16) * PSLD + quad * 8];
#pragma unroll
        for (int nt = 0; nt < 2; ++nt) {
            int dv = n0o + nt * 16 + lane16;
            bb[nt] = *(const half8*)&VT[((size_t)bh * DKV + dv) * T_SEQ + c * CHUNK_L + s * 32 + quad * 8];
        }
#pragma unroll
        for (int mt = 0; mt < 4; ++mt)
#pragma unroll
            for (int nt = 0; nt < 2; ++nt)
                accO[mt][nt] = __builtin_amdgcn_mfma_f32_16x16x32_f16(a[mt], bb[nt], accO[mt][nt], 0, 0, 0);
    }

    const _Float16* gh = Gh + ((size_t)bh * NCH + c) * (DKV * DKV);
#pragma unroll
    for (int s = 0; s < 4; ++s) {
        half8 a[4], bb[2];
#pragma unroll
        for (int mt = 0; mt < 4; ++mt)
            a[mt] = *(const half8*)&Qf[(rowbase + mt * 16 + lane16) * HIDDEN +
                                       h * DKV + s * 32 + quad * 8];
#pragma unroll
        for (int nt = 0; nt < 2; ++nt) {
            int dv = n0o + nt * 16 + lane16;
            bb[nt] = *(const half8*)&gh[(size_t)dv * DKV + s * 32 + quad * 8];
        }
#pragma unroll
        for (int mt = 0; mt < 4; ++mt)
#pragma unroll
            for (int nt = 0; nt < 2; ++nt)
                accO[mt][nt] = __builtin_amdgcn_mfma_f32_16x16x32_f16(a[mt], bb[nt], accO[mt][nt], 0, 0, 0);
    }

#pragma unroll
    for (int mt = 0; mt < 4; ++mt)
#pragma unroll
        for (int nt = 0; nt < 2; ++nt)
#pragma unroll
            for (int r = 0; r < 4; ++r)
                O[(rowbase + mt * 16 + quad * 4 + r) * HIDDEN + h * DKV + n0o + nt * 16 + lane16] =
                    (_Float16)(accO[mt][nt][r] * OEPS);
}

// ---------------------------------------------------------------------------
// Workspace map (192 MiB, fully DISJOINT):
//   [0,16)    h16 (P0-P1) -> qf16 (P3-P6)
//   [16,32)   weights (whole run)
//   [32,80)   qkvlin (P1-P3)
//   [80,96)   kf16 (P3-P6)
//   [96,112)  vT (P2-P6)
//   [112,128) O16 (P6-P7)
//   [128,160) G16 fp16 (P4-P5)
//   [160,192) Gh fp16 (P5-P6)
// ---------------------------------------------------------------------------
extern "C" void kernel_launch(void* const* d_in, const int* in_sizes, int n_in,
                              void* d_out, int out_size, void* d_ws, size_t ws_size,
                              hipStream_t stream)
{
    (void)in_sizes; (void)n_in; (void)out_size; (void)ws_size;
    const float* hs = (const float*)d_in[0];
    const float* wq = (const float*)d_in[1];
    const float* wk = (const float*)d_in[2];
    const float* wv = (const float*)d_in[3];
    const float* wo = (const float*)d_in[4];
    const float* cq = (const float*)d_in[5];
    const float* ck = (const float*)d_in[6];
    const float* cv = (const float*)d_in[7];
    const float* fmq_w1 = (const float*)d_in[8];
    const float* fmq_b1 = (const float*)d_in[9];
    const float* fmq_w2 = (const float*)d_in[10];
    const float* fmq_b2 = (const float*)d_in[11];
    const float* fmk_w1 = (const float*)d_in[12];
    const float* fmk_b1 = (const float*)d_in[13];
    const float* fmk_w2 = (const float*)d_in[14];
    const float* fmk_b2 = (const float*)d_in[15];
    float* out = (float*)d_out;
    char* ws = (char*)d_ws;

    const size_t MB = 1024 * 1024;
    _Float16* h16     = (_Float16*)(ws + 0);
    _Float16* qf16    = (_Float16*)(ws + 0);
    _Float16* wqkv16  = (_Float16*)(ws + 16 * MB);         // 3072x1024
    _Float16* wo16    = wqkv16 + (3 << 20);
    _Float16* fmw     = wqkv16 + (4 << 20);                // 4 x 16384
    _Float16* qkvlin  = (_Float16*)(ws + 32 * MB);         // [8192][3072]
    _Float16* kf16    = (_Float16*)(ws + 80 * MB);
    _Float16* vT      = (_Float16*)(ws + 96 * MB);
    _Float16* O16     = (_Float16*)(ws + 112 * MB);
    _Float16* G16     = (_Float16*)(ws + 128 * MB);        // 32 MB fp16
    _Float16* Gh      = (_Float16*)(ws + 160 * MB);        // 32 MB fp16

    // ---- P0: casts ----
    cast_f32_f16<<<4096, 256, 0, stream>>>(hs, h16, BT * HIDDEN / 8);
    cast8_f32_f16<<<dim3(512, 8), 256, 0, stream>>>(
        wq, wk, wv, wo, fmq_w1, fmq_w2, fmk_w1, fmk_w2,
        wqkv16, wqkv16 + (1 << 20), wqkv16 + (2 << 20), wo16,
        fmw, fmw + 16384, fmw + 2 * 16384, fmw + 3 * 16384,
        HIDDEN * HIDDEN / 8, DKV * DKV / 8);

    // ---- P1: fused QKV projection (N = 3072), 256x256 8-phase ----
    dim3 gqkv(3 * HIDDEN / 256, BT / 256);   // (12, 32) = 384 blocks
    gemm256_nt_f16_h16<<<gqkv, 512, 0, stream>>>(h16, wqkv16, qkvlin, BT, 3 * HIDDEN, HIDDEN);

    // ---- P2: conv + silu for V (transposed out) ----
    conv_silu_T<<<2048, 256, 0, stream>>>(qkvlin + 2 * HIDDEN, 3 * HIDDEN, cv, vT);

    // ---- P3: FUSED conv + feature map for q,k (v2 weight-amortized) ----
    dim3 fg(BT / 64, NHEAD, 2);
    convfm<<<fg, 256, 0, stream>>>(qkvlin, 3 * HIDDEN, cq, ck, fmw,
                                   fmq_b1, fmq_b2, fmk_b1, fmk_b2, qf16, kf16);

    // ---- P4-P6: chunked linear attention ----
    dim3 ag(NCH, BATCH * NHEAD);
    ktv_mfma<<<ag, 256, 0, stream>>>(kf16, vT, G16);
    prefix_kernel<<<(16 * 16384) / 256, 256, 0, stream>>>(G16, Gh);
    attn_mfma<<<ag, 256, 0, stream>>>(qf16, kf16, vT, Gh, O16);

    // ---- P7: output projection (undo SCALE_O), BK=64 ----
    dim3 gg(HIDDEN / 128, BT / 128);
    gemm_nt_f16_f32<<<gg, 256, 0, stream>>>(O16, wo16, out, BT, HIDDEN, HIDDEN, 1.0f / SCALE_O);
}

// Round 2
// 313.375 us; speedup vs baseline: 1.0433x; 1.0267x over previous
//
#include <hip/hip_runtime.h>
#include <cstdint>
#include <cstddef>

#define T_SEQ 4096
#define BATCH 2
#define HIDDEN 1024
#define NHEAD 8
#define DKV 128
#define BT (BATCH * T_SEQ)   // 8192
#define NCH 64               // chunks per batch
#define CHUNK_L 64
#define QSCALE 0.08838834764831845f
#define SCALE_P 1024.0f
#define SCALE_O 8192.0f
#define OEPS 0.7071067811865476f

typedef _Float16 half8 __attribute__((ext_vector_type(8)));
typedef float floatx4 __attribute__((ext_vector_type(4)));

union HBits { _Float16 h; unsigned short u; };

// ---------------------------------------------------------------------------
// fp32 -> fp16 cast, 8 elements/thread
// ---------------------------------------------------------------------------
__global__ void cast_f32_f16(const float* __restrict__ X, _Float16* __restrict__ Y, int n8)
{
    int idx = blockIdx.x * 256 + threadIdx.x;
    if (idx < n8) {
        float4 a = ((const float4*)X)[idx * 2];
        float4 b = ((const float4*)X)[idx * 2 + 1];
        half8 h = { (_Float16)a.x, (_Float16)a.y, (_Float16)a.z, (_Float16)a.w,
                    (_Float16)b.x, (_Float16)b.y, (_Float16)b.z, (_Float16)b.w };
        *(half8*)&Y[idx * 8] = h;
    }
}

// 8 weight tensors in one launch; blockIdx.y selects.
__global__ void cast8_f32_f16(const float* __restrict__ s0, const float* __restrict__ s1,
                              const float* __restrict__ s2, const float* __restrict__ s3,
                              const float* __restrict__ s4, const float* __restrict__ s5,
                              const float* __restrict__ s6, const float* __restrict__ s7,
                              _Float16* __restrict__ d0, _Float16* __restrict__ d1,
                              _Float16* __restrict__ d2, _Float16* __restrict__ d3,
                              _Float16* __restrict__ d4, _Float16* __restrict__ d5,
                              _Float16* __restrict__ d6, _Float16* __restrict__ d7,
                              int nbig, int nsmall)
{
    int sel = blockIdx.y;
    const float* src; _Float16* dst; int n8;
    switch (sel) {
        case 0: src = s0; dst = d0; n8 = nbig; break;
        case 1: src = s1; dst = d1; n8 = nbig; break;
        case 2: src = s2; dst = d2; n8 = nbig; break;
        case 3: src = s3; dst = d3; n8 = nbig; break;
        case 4: src = s4; dst = d4; n8 = nsmall; break;
        case 5: src = s5; dst = d5; n8 = nsmall; break;
        case 6: src = s6; dst = d6; n8 = nsmall; break;
        default: src = s7; dst = d7; n8 = nsmall; break;
    }
    int idx = blockIdx.x * 256 + threadIdx.x;
    if (idx < n8) {
        float4 u = ((const float4*)src)[idx * 2];
        float4 v = ((const float4*)src)[idx * 2 + 1];
        half8 h = { (_Float16)u.x, (_Float16)u.y, (_Float16)u.z, (_Float16)u.w,
                    (_Float16)v.x, (_Float16)v.y, (_Float16)v.z, (_Float16)v.w };
        *(half8*)&dst[idx * 8] = h;
    }
}

// ---------------------------------------------------------------------------
// GEMM (NT) fp16 MFMA, fp16 out: 128x128 tile, BK=64, 4 waves, XOR-swizzled
// LDS columns (proven ~740 TF here, 0 bank conflicts).  R2: + bijective
// XCD-aware blockIdx swizzle (T1): each XCD owns 8 contiguous row-bands ->
// A-panel L2 reuse.  nwg must be divisible by 8 (1536 / 512: yes).
// ---------------------------------------------------------------------------
__global__ __launch_bounds__(256) void gemm_nt_f16_h16(const _Float16* __restrict__ A,
                                                       const _Float16* __restrict__ W,
                                                       _Float16* __restrict__ C,
                                                       int M, int N, int K)
{
    __shared__ _Float16 As[128 * 64];
    __shared__ _Float16 Ws[128 * 64];
    const int nwg = gridDim.x * gridDim.y;
    const int bid = blockIdx.y * gridDim.x + blockIdx.x;
    const int swz = (bid & 7) * (nwg >> 3) + (bid >> 3);
    const int bm = (swz / gridDim.x) * 128;
    const int bn = (swz % gridDim.x) * 128;
    const int tid = threadIdx.x;
    const int w = tid >> 6;
    const int l = tid & 63;
    const int wm = (w >> 1) * 64;
    const int wn = (w & 1) * 64;
    const int lane16 = l & 15;
    const int quad = l >> 4;
    const int srow = w * 8 + (l >> 3);
    const int skh = ((l & 7) ^ (l >> 3)) * 8;
    const int rsw = lane16 & 7;

    floatx4 acc[4][4];
#pragma unroll
    for (int i = 0; i < 4; ++i)
#pragma unroll
        for (int j = 0; j < 4; ++j)
            acc[i][j] = (floatx4){0.f, 0.f, 0.f, 0.f};

    for (int k0 = 0; k0 < K; k0 += 64) {
#pragma unroll
        for (int c = 0; c < 4; ++c) {
            int row = c * 32 + srow;
            const _Float16* ga = A + (size_t)(bm + row) * K + k0 + skh;
            const _Float16* gw = W + (size_t)(bn + row) * K + k0 + skh;
            __builtin_amdgcn_global_load_lds(
                (const __attribute__((address_space(1))) void*)ga,
                (__attribute__((address_space(3))) void*)(As + c * 2048 + w * 512), 16, 0, 0);
            __builtin_amdgcn_global_load_lds(
                (const __attribute__((address_space(1))) void*)gw,
                (__attribute__((address_space(3))) void*)(Ws + c * 2048 + w * 512), 16, 0, 0);
        }
        __syncthreads();

#pragma unroll
        for (int s = 0; s < 2; ++s) {
            const int pc = (((s * 4 + quad) ^ rsw)) * 8;
            half8 a[4], b[4];
#pragma unroll
            for (int i = 0; i < 4; ++i) {
                a[i] = *(const half8*)&As[(wm + i * 16 + lane16) * 64 + pc];
                b[i] = *(const half8*)&Ws[(wn + i * 16 + lane16) * 64 + pc];
            }
#pragma unroll
            for (int i = 0; i < 4; ++i)
#pragma unroll
                for (int j = 0; j < 4; ++j)
                    acc[i][j] = __builtin_amdgcn_mfma_f32_16x16x32_f16(a[i], b[j], acc[i][j], 0, 0, 0);
        }
        __syncthreads();
    }
#pragma unroll
    for (int i = 0; i < 4; ++i)
#pragma unroll
        for (int j = 0; j < 4; ++j)
#pragma unroll
            for (int r = 0; r < 4; ++r)
                C[(size_t)(bm + wm + i * 16 + quad * 4 + r) * N + bn + wn + j * 16 + lane16] =
                    (_Float16)acc[i][j][r];
}

// ---------------------------------------------------------------------------
// Same BK=64 structure, fp32 out with scale (final projection; undoes
// SCALE_O).  + XCD swizzle (512 blocks, divisible by 8).
// ---------------------------------------------------------------------------
__global__ __launch_bounds__(256) void gemm_nt_f16_f32(const _Float16* __restrict__ A,
                                                       const _Float16* __restrict__ W,
                                                       float* __restrict__ C,
                                                       int M, int N, int K, float scale)
{
    __shared__ _Float16 As[128 * 64];
    __shared__ _Float16 Ws[128 * 64];
    const int nwg = gridDim.x * gridDim.y;
    const int bid = blockIdx.y * gridDim.x + blockIdx.x;
    const int swz = (bid & 7) * (nwg >> 3) + (bid >> 3);
    const int bm = (swz / gridDim.x) * 128;
    const int bn = (swz % gridDim.x) * 128;
    const int tid = threadIdx.x;
    const int w = tid >> 6;
    const int l = tid & 63;
    const int wm = (w >> 1) * 64;
    const int wn = (w & 1) * 64;
    const int lane16 = l & 15;
    const int quad = l >> 4;
    const int srow = w * 8 + (l >> 3);
    const int skh = ((l & 7) ^ (l >> 3)) * 8;
    const int rsw = lane16 & 7;

    floatx4 acc[4][4];
#pragma unroll
    for (int i = 0; i < 4; ++i)
#pragma unroll
        for (int j = 0; j < 4; ++j)
            acc[i][j] = (floatx4){0.f, 0.f, 0.f, 0.f};

    for (int k0 = 0; k0 < K; k0 += 64) {
#pragma unroll
        for (int c = 0; c < 4; ++c) {
            int row = c * 32 + srow;
            const _Float16* ga = A + (size_t)(bm + row) * K + k0 + skh;
            const _Float16* gw = W + (size_t)(bn + row) * K + k0 + skh;
            __builtin_amdgcn_global_load_lds(
                (const __attribute__((address_space(1))) void*)ga,
                (__attribute__((address_space(3))) void*)(As + c * 2048 + w * 512), 16, 0, 0);
            __builtin_amdgcn_global_load_lds(
                (const __attribute__((address_space(1))) void*)gw,
                (__attribute__((address_space(3))) void*)(Ws + c * 2048 + w * 512), 16, 0, 0);
        }
        __syncthreads();

#pragma unroll
        for (int s = 0; s < 2; ++s) {
            const int pc = (((s * 4 + quad) ^ rsw)) * 8;
            half8 a[4], b[4];
#pragma unroll
            for (int i = 0; i < 4; ++i) {
                a[i] = *(const half8*)&As[(wm + i * 16 + lane16) * 64 + pc];
                b[i] = *(const half8*)&Ws[(wn + i * 16 + lane16) * 64 + pc];
            }
#pragma unroll
            for (int i = 0; i < 4; ++i)
#pragma unroll
                for (int j = 0; j < 4; ++j)
                    acc[i][j] = __builtin_amdgcn_mfma_f32_16x16x32_f16(a[i], b[j], acc[i][j], 0, 0, 0);
        }
        __syncthreads();
    }
#pragma unroll
    for (int i = 0; i < 4; ++i)
#pragma unroll
        for (int j = 0; j < 4; ++j)
#pragma unroll
            for (int r = 0; r < 4; ++r)
                C[(size_t)(bm + wm + i * 16 + quad * 4 + r) * N + bn + wn + j * 16 + lane16] =
                    acc[i][j][r] * scale;
}

// ---------------------------------------------------------------------------
// Conv + SiLU for V, writing TRANSPOSED: vT[b*1024 + d][t]  (fp16).
// grid.x = 2048 = 64 ttiles * 16 dtiles * 2 batch.
// ---------------------------------------------------------------------------
__global__ __launch_bounds__(256) void conv_silu_T(const _Float16* __restrict__ X, int ldx,
                                                   const float* __restrict__ Wc,
                                                   _Float16* __restrict__ VT)
{
    __shared__ _Float16 xs[67 * 64];
    const int bx = blockIdx.x;
    const int t0 = (bx & 63) * 64;
    const int dt = ((bx >> 6) & 15) * 64;
    const int z = bx >> 10;
    const int tid = threadIdx.x;

#pragma unroll
    for (int i = 0; i < 3; ++i) {
        int p = tid + 256 * i;
        if (p < 536) {
            int row = p >> 3, d8 = (p & 7) * 8;
            int t = t0 - 3 + row;
            half8 v;
            if (t >= 0)
                v = *(const half8*)&X[((size_t)z * T_SEQ + t) * ldx + dt + d8];
            else
                v = (half8){0, 0, 0, 0, 0, 0, 0, 0};
            *(half8*)&xs[row * 64 + d8] = v;
        }
    }
    __syncthreads();

    const int d = tid & 63;
    const int dg = dt + d;
    float4 w = *(const float4*)&Wc[dg * 4];
#pragma unroll
    for (int u = 0; u < 2; ++u) {
        int tg = (tid >> 6) + u * 4;
        half8 o;
#pragma unroll
        for (int s = 0; s < 8; ++s) {
            int base = (tg * 8 + s + 3) * 64 + d;
            float acc = (float)xs[base] * w.w
                      + (float)xs[base - 64] * w.z
                      + (float)xs[base - 128] * w.y
                      + (float)xs[base - 192] * w.x;
            o[s] = (_Float16)(acc / (1.f + __expf(-acc)));
        }
        *(half8*)&VT[((size_t)z * HIDDEN + dg) * T_SEQ + t0 + tg * 8] = o;
    }
}

// ---------------------------------------------------------------------------
// FUSED conv+SiLU + feature map (q/k via blockIdx.z), v3.
// R2: fm-weight B-operands software-pipelined — s=0 fragments + biases are
// loaded at kernel ENTRY (latency hidden behind input staging + conv), and
// s+1 fragments are issued under s's MFMAs.  Same loads / same MFMA order ->
// bit-identical results.
// ---------------------------------------------------------------------------
#define XIN_LD 136   // 67 rows x 136 halfs
__global__ __launch_bounds__(256) void convfm(const _Float16* __restrict__ QKV, int ldx,
                                              const float* __restrict__ Wcq,
                                              const float* __restrict__ Wck,
                                              const _Float16* __restrict__ Wfm,  // 4x16384
                                              const float* __restrict__ Bq1,
                                              const float* __restrict__ Bq2,
                                              const float* __restrict__ Bk1,
                                              const float* __restrict__ Bk2,
                                              _Float16* __restrict__ OUTq,
                                              _Float16* __restrict__ OUTk)
{
    const int sel = blockIdx.z;
    const float* Wc = sel ? Wck : Wcq;
    const _Float16* W1h = Wfm + (sel ? 2 * 16384 : 0);
    const _Float16* W2h = Wfm + (sel ? 3 * 16384 : 16384);
    const float* B1 = sel ? Bk1 : Bq1;
    const float* B2 = sel ? Bk2 : Bq2;
    _Float16* OUT = sel ? OUTk : OUTq;

    __shared__ _Float16 xin[67 * XIN_LD];    // input window (t0-3 .. t0+63) x 128
    __shared__ _Float16 xs[4 * 64 * 32];     // conv output, MFMA staging layout
    const int t0 = blockIdx.x * 64;
    const int h = blockIdx.y;
    const int tid = threadIdx.x;
    const int w = tid >> 6;
    const int l = tid & 63;
    const int lane16 = l & 15;
    const int quad = l >> 4;
    const bool batch_start = (t0 & (T_SEQ - 1)) == 0;
    const int ebase = w * 32 + lane16;

    // ---- entry prefetch: s=0 fm-weight fragments + biases (T14) ----
    half8 pb1[2], pb2[2];
    float b1v[2], b2v[2];
#pragma unroll
    for (int nt = 0; nt < 2; ++nt) {
        pb1[nt] = *(const half8*)&W1h[(size_t)(ebase + nt * 16) * DKV + quad * 8];
        pb2[nt] = *(const half8*)&W2h[(size_t)(ebase + nt * 16) * DKV + quad * 8];
        b1v[nt] = B1[ebase + nt * 16];
        b2v[nt] = B2[ebase + nt * 16];
    }

    // ---- stage input window: 67 rows x 16 col-groups = 1072 half8 ----
    for (int p = tid; p < 67 * 16; p += 256) {
        int row = p >> 4, cg = p & 15;
        half8 v;
        if (batch_start && row < 3)
            v = (half8){0, 0, 0, 0, 0, 0, 0, 0};
        else
            v = *(const half8*)&QKV[(size_t)(t0 - 3 + row) * ldx + sel * HIDDEN + h * DKV + cg * 8];
        *(half8*)&xin[row * XIN_LD + cg * 8] = v;
    }
    __syncthreads();

    // ---- conv + silu: thread owns 8 channels (d-oct) x 4 rows ----
    {
        const int doct = tid & 15;       // d0 = doct*8
        const int d0 = doct * 8;
        const int rq = (tid >> 4) * 4;   // rows rq..rq+3
        const int u = doct >> 2;         // kstep slab in xs
        const int col = d0 & 31;

        float w0[8], w1[8], w2[8], w3[8];
#pragma unroll
        for (int e = 0; e < 8; ++e) {
            float4 wv = *(const float4*)&Wc[(h * DKV + d0 + e) * 4];
            w0[e] = wv.x; w1[e] = wv.y; w2[e] = wv.z; w3[e] = wv.w;
        }

#pragma unroll
        for (int rr = 0; rr < 4; ++rr) {
            const int row = rq + rr;
            half8 x3 = *(const half8*)&xin[(row + 0) * XIN_LD + d0];
            half8 x2 = *(const half8*)&xin[(row + 1) * XIN_LD + d0];
            half8 x1 = *(const half8*)&xin[(row + 2) * XIN_LD + d0];
            half8 x0 = *(const half8*)&xin[(row + 3) * XIN_LD + d0];
            half8 o;
#pragma unroll
            for (int e = 0; e < 8; ++e) {
                float acc = fmaf((float)x0[e], w3[e],
                            fmaf((float)x1[e], w2[e],
                            fmaf((float)x2[e], w1[e], (float)x3[e] * w0[e])));
                o[e] = (_Float16)(acc / (1.f + __expf(-acc)));
            }
            *(half8*)&xs[u * 2048 + row * 32 + col] = o;
        }
    }
    __syncthreads();

    // ---- dual GEMM + hadamard (B-fragments pipelined depth-1) ----
    floatx4 acc1[4][2], acc2[4][2];
#pragma unroll
    for (int i = 0; i < 4; ++i)
#pragma unroll
        for (int j = 0; j < 2; ++j) {
            acc1[i][j] = (floatx4){0.f, 0.f, 0.f, 0.f};
            acc2[i][j] = (floatx4){0.f, 0.f, 0.f, 0.f};
        }

#pragma unroll
    for (int s = 0; s < 4; ++s) {
        half8 nb1[2], nb2[2];
        if (s < 3) {
#pragma unroll
            for (int nt = 0; nt < 2; ++nt) {
                nb1[nt] = *(const half8*)&W1h[(size_t)(ebase + nt * 16) * DKV + (s + 1) * 32 + quad * 8];
                nb2[nt] = *(const half8*)&W2h[(size_t)(ebase + nt * 16) * DKV + (s + 1) * 32 + quad * 8];
            }
        }
        half8 a[4];
#pragma unroll
        for (int mt = 0; mt < 4; ++mt)
            a[mt] = *(const half8*)&xs[s * 2048 + (mt * 16 + lane16) * 32 + quad * 8];
#pragma unroll
        for (int nt = 0; nt < 2; ++nt) {
#pragma unroll
            for (int mt = 0; mt < 4; ++mt) {
                acc1[mt][nt] = __builtin_amdgcn_mfma_f32_16x16x32_f16(a[mt], pb1[nt], acc1[mt][nt], 0, 0, 0);
                acc2[mt][nt] = __builtin_amdgcn_mfma_f32_16x16x32_f16(a[mt], pb2[nt], acc2[mt][nt], 0, 0, 0);
            }
        }
        if (s < 3) {
            pb1[0] = nb1[0]; pb1[1] = nb1[1];
            pb2[0] = nb2[0]; pb2[1] = nb2[1];
        }
    }

#pragma unroll
    for (int nt = 0; nt < 2; ++nt) {
#pragma unroll
        for (int mt = 0; mt < 4; ++mt)
#pragma unroll
            for (int r = 0; r < 4; ++r) {
                float o = (acc1[mt][nt][r] + b1v[nt]) * (acc2[mt][nt][r] + b2v[nt]);
                OUT[(size_t)(t0 + mt * 16 + quad * 4 + r) * HIDDEN + h * DKV + ebase + nt * 16] = (_Float16)o;
            }
    }
}

// ---------------------------------------------------------------------------
// Per-chunk S^T[dv][dk] = sum_j V[j][dv] K[j][dk], MFMA. fp16 out.
// R2: VT a-fragments hoisted to kernel entry (hidden behind K LDS transpose).
// ---------------------------------------------------------------------------
__global__ __launch_bounds__(256) void ktv_mfma(const _Float16* __restrict__ Kf,
                                                const _Float16* __restrict__ VT,
                                                _Float16* __restrict__ G16)
{
    __shared__ _Float16 kt[128 * 72];
    const int c = blockIdx.x;
    const int bh = blockIdx.y;
    const int b = bh >> 3, h = bh & 7;
    const int tid = threadIdx.x;
    const int w = tid >> 6;
    const int l = tid & 63;
    const int lane16 = l & 15;
    const int quad = l >> 4;
    const size_t rowbase = (size_t)b * T_SEQ + (size_t)c * CHUNK_L;

    // entry prefetch of all 8 VT fragments (T14)
    const int m0 = (w >> 1) * 64;
    const int n0 = (w & 1) * 64;
    half8 vta[2][4];
#pragma unroll
    for (int s = 0; s < 2; ++s)
#pragma unroll
        for (int mt = 0; mt < 4; ++mt) {
            int dv = m0 + mt * 16 + lane16;
            vta[s][mt] = *(const half8*)&VT[((size_t)bh * DKV + dv) * T_SEQ + c * CHUNK_L + s * 32 + quad * 8];
        }

    {
        const int dk0 = (tid >> 4) * 8;
        const int jb = (tid & 15) * 4;
        half8 r0 = *(const half8*)&Kf[(rowbase + jb + 0) * HIDDEN + h * DKV + dk0];
        half8 r1 = *(const half8*)&Kf[(rowbase + jb + 1) * HIDDEN + h * DKV + dk0];
        half8 r2 = *(const half8*)&Kf[(rowbase + jb + 2) * HIDDEN + h * DKV + dk0];
        half8 r3 = *(const half8*)&Kf[(rowbase + jb + 3) * HIDDEN + h * DKV + dk0];
#pragma unroll
        for (int dk = 0; dk < 8; ++dk) {
            HBits a0, a1, a2, a3;
            a0.h = r0[dk]; a1.h = r1[dk]; a2.h = r2[dk]; a3.h = r3[dk];
            unsigned int lo = ((unsigned int)a1.u << 16) | a0.u;
            unsigned int hi = ((unsigned int)a3.u << 16) | a2.u;
            *(unsigned int*)&kt[(dk0 + dk) * 72 + jb] = lo;
            *(unsigned int*)&kt[(dk0 + dk) * 72 + jb + 2] = hi;
        }
    }
    __syncthreads();

    floatx4 acc[4][4];
#pragma unroll
    for (int i = 0; i < 4; ++i)
#pragma unroll
        for (int j = 0; j < 4; ++j)
            acc[i][j] = (floatx4){0.f, 0.f, 0.f, 0.f};

#pragma unroll
    for (int s = 0; s < 2; ++s) {
        half8 bb[4];
#pragma unroll
        for (int nt = 0; nt < 4; ++nt)
            bb[nt] = *(const half8*)&kt[(n0 + nt * 16 + lane16) * 72 + s * 32 + quad * 8];
#pragma unroll
        for (int mt = 0; mt < 4; ++mt)
#pragma unroll
            for (int nt = 0; nt < 4; ++nt)
                acc[mt][nt] = __builtin_amdgcn_mfma_f32_16x16x32_f16(vta[s][mt], bb[nt], acc[mt][nt], 0, 0, 0);
    }

    _Float16* Gp = G16 + ((size_t)bh * NCH + c) * (DKV * DKV);
#pragma unroll
    for (int mt = 0; mt < 4; ++mt)
#pragma unroll
        for (int nt = 0; nt < 4; ++nt)
#pragma unroll
            for (int r = 0; r < 4; ++r)
                Gp[(size_t)(m0 + mt * 16 + quad * 4 + r) * DKV + n0 + nt * 16 + lane16] =
                    (_Float16)acc[mt][nt][r];
}

// ---------------------------------------------------------------------------
// Exclusive prefix over chunks; fp32 running sum; Gh fp16 (scaled SCALE_P).
// ---------------------------------------------------------------------------
__global__ void prefix_kernel(const _Float16* __restrict__ G16, _Float16* __restrict__ Gh)
{
    int idx = blockIdx.x * 256 + threadIdx.x;   // 16 * 16384
    int bh = idx >> 14;
    int e = idx & 16383;
    const _Float16* p = G16 + (size_t)bh * NCH * 16384 + e;
    _Float16* q = Gh + (size_t)bh * NCH * 16384 + e;
    float run = 0.f;
#pragma unroll
    for (int c = 0; c < NCH; ++c) {
        q[(size_t)c * 16384] = (_Float16)(run * SCALE_P);
        run += (float)p[(size_t)c * 16384];
    }
}

// ---------------------------------------------------------------------------
// Attention per chunk, MFMA.
// R2: part-2 VT fragments + part-3 s=0 Gh fragments loaded at ENTRY (latency
// hidden behind the QK^T section); remaining Gh fragments pipelined depth-1.
// ---------------------------------------------------------------------------
#define PSLD 40
__global__ __launch_bounds__(256) void attn_mfma(const _Float16* __restrict__ Qf,
                                                 const _Float16* __restrict__ Kf,
                                                 const _Float16* __restrict__ VT,
                                                 const _Float16* __restrict__ Gh,
                                                 _Float16* __restrict__ O)
{
    __shared__ _Float16 ps[2 * 64 * PSLD];
    const int c = blockIdx.x;
    const int bh = blockIdx.y;
    const int b = bh >> 3, h = bh & 7;
    const int tid = threadIdx.x;
    const int w = tid >> 6;
    const int l = tid & 63;
    const int lane16 = l & 15;
    const int quad = l >> 4;
    const size_t rowbase = (size_t)b * T_SEQ + (size_t)c * CHUNK_L;
    const int n0o = w * 32;
    const _Float16* gh = Gh + ((size_t)bh * NCH + c) * (DKV * DKV);

    // ---- entry prefetch (T14): VT for part 2, s=0 Gh for part 3 ----
    half8 vtpre[2][2];
#pragma unroll
    for (int s = 0; s < 2; ++s)
#pragma unroll
        for (int nt = 0; nt < 2; ++nt) {
            int dv = n0o + nt * 16 + lane16;
            vtpre[s][nt] = *(const half8*)&VT[((size_t)bh * DKV + dv) * T_SEQ + c * CHUNK_L + s * 32 + quad * 8];
        }
    half8 ghp[2];
#pragma unroll
    for (int nt = 0; nt < 2; ++nt)
        ghp[nt] = *(const half8*)&gh[(size_t)(n0o + nt * 16 + lane16) * DKV + quad * 8];

    {
        const int m0 = (w >> 1) * 32;
        const int n0 = (w & 1) * 32;
        floatx4 aq[2][2];
#pragma unroll
        for (int i = 0; i < 2; ++i)
#pragma unroll
            for (int j = 0; j < 2; ++j)
                aq[i][j] = (floatx4){0.f, 0.f, 0.f, 0.f};
#pragma unroll
        for (int s = 0; s < 4; ++s) {
            half8 a[2], bb[2];
#pragma unroll
            for (int mt = 0; mt < 2; ++mt)
                a[mt] = *(const half8*)&Qf[(rowbase + m0 + mt * 16 + lane16) * HIDDEN +
                                           h * DKV + s * 32 + quad * 8];
#pragma unroll
            for (int nt = 0; nt < 2; ++nt)
                bb[nt] = *(const half8*)&Kf[(rowbase + n0 + nt * 16 + lane16) * HIDDEN +
                                            h * DKV + s * 32 + quad * 8];
#pragma unroll
            for (int mt = 0; mt < 2; ++mt)
#pragma unroll
                for (int nt = 0; nt < 2; ++nt)
                    aq[mt][nt] = __builtin_amdgcn_mfma_f32_16x16x32_f16(a[mt], bb[nt], aq[mt][nt], 0, 0, 0);
        }
#pragma unroll
        for (int mt = 0; mt < 2; ++mt)
#pragma unroll
            for (int nt = 0; nt < 2; ++nt) {
                int j = n0 + nt * 16 + lane16;
#pragma unroll
                for (int r = 0; r < 4; ++r) {
                    int i = m0 + mt * 16 + quad * 4 + r;
                    float v = (j <= i) ? aq[mt][nt][r] * SCALE_P : 0.f;
                    ps[(j >> 5) * 64 * PSLD + i * PSLD + (j & 31)] = (_Float16)v;
                }
            }
    }
    __syncthreads();

    floatx4 accO[4][2];
#pragma unroll
    for (int i = 0; i < 4; ++i)
#pragma unroll
        for (int j = 0; j < 2; ++j)
            accO[i][j] = (floatx4){0.f, 0.f, 0.f, 0.f};

#pragma unroll
    for (int s = 0; s < 2; ++s) {
        half8 a[4];
#pragma unroll
        for (int mt = 0; mt < 4; ++mt)
            a[mt] = *(const half8*)&ps[s * 64 * PSLD + (mt * 16 + lane16) * PSLD + quad * 8];
#pragma unroll
        for (int mt = 0; mt < 4; ++mt)
#pragma unroll
            for (int nt = 0; nt < 2; ++nt)
                accO[mt][nt] = __builtin_amdgcn_mfma_f32_16x16x32_f16(a[mt], vtpre[s][nt], accO[mt][nt], 0, 0, 0);
    }

#pragma unroll
    for (int s = 0; s < 4; ++s) {
        half8 nb[2];
        if (s < 3) {
#pragma unroll
            for (int nt = 0; nt < 2; ++nt)
                nb[nt] = *(const half8*)&gh[(size_t)(n0o + nt * 16 + lane16) * DKV + (s + 1) * 32 + quad * 8];
        }
        half8 a[4];
#pragma unroll
        for (int mt = 0; mt < 4; ++mt)
            a[mt] = *(const half8*)&Qf[(rowbase + mt * 16 + lane16) * HIDDEN +
                                       h * DKV + s * 32 + quad * 8];
#pragma unroll
        for (int mt = 0; mt < 4; ++mt)
#pragma unroll
            for (int nt = 0; nt < 2; ++nt)
                accO[mt][nt] = __builtin_amdgcn_mfma_f32_16x16x32_f16(a[mt], ghp[nt], accO[mt][nt], 0, 0, 0);
        if (s < 3) { ghp[0] = nb[0]; ghp[1] = nb[1]; }
    }

#pragma unroll
    for (int mt = 0; mt < 4; ++mt)
#pragma unroll
        for (int nt = 0; nt < 2; ++nt)
#pragma unroll
            for (int r = 0; r < 4; ++r)
                O[(rowbase + mt * 16 + quad * 4 + r) * HIDDEN + h * DKV + n0o + nt * 16 + lane16] =
                    (_Float16)(accO[mt][nt][r] * OEPS);
}

// ---------------------------------------------------------------------------
// Workspace map (192 MiB, fully DISJOINT):
//   [0,16)    h16 (P0-P1) -> qf16 (P3-P6)
//   [16,32)   weights (whole run)
//   [32,80)   qkvlin (P1-P3)
//   [80,96)   kf16 (P3-P6)
//   [96,112)  vT (P2-P6)
//   [112,128) O16 (P6-P7)
//   [128,160) G16 fp16 (P4-P5)
//   [160,192) Gh fp16 (P5-P6)
// ---------------------------------------------------------------------------
extern "C" void kernel_launch(void* const* d_in, const int* in_sizes, int n_in,
                              void* d_out, int out_size, void* d_ws, size_t ws_size,
                              hipStream_t stream)
{
    (void)in_sizes; (void)n_in; (void)out_size; (void)ws_size;
    const float* hs = (const float*)d_in[0];
    const float* wq = (const float*)d_in[1];
    const float* wk = (const float*)d_in[2];
    const float* wv = (const float*)d_in[3];
    const float* wo = (const float*)d_in[4];
    const float* cq = (const float*)d_in[5];
    const float* ck = (const float*)d_in[6];
    const float* cv = (const float*)d_in[7];
    const float* fmq_w1 = (const float*)d_in[8];
    const float* fmq_b1 = (const float*)d_in[9];
    const float* fmq_w2 = (const float*)d_in[10];
    const float* fmq_b2 = (const float*)d_in[11];
    const float* fmk_w1 = (const float*)d_in[12];
    const float* fmk_b1 = (const float*)d_in[13];
    const float* fmk_w2 = (const float*)d_in[14];
    const float* fmk_b2 = (const float*)d_in[15];
    float* out = (float*)d_out;
    char* ws = (char*)d_ws;

    const size_t MB = 1024 * 1024;
    _Float16* h16     = (_Float16*)(ws + 0);
    _Float16* qf16    = (_Float16*)(ws + 0);
    _Float16* wqkv16  = (_Float16*)(ws + 16 * MB);         // 3072x1024
    _Float16* wo16    = wqkv16 + (3 << 20);
    _Float16* fmw     = wqkv16 + (4 << 20);                // 4 x 16384
    _Float16* qkvlin  = (_Float16*)(ws + 32 * MB);         // [8192][3072]
    _Float16* kf16    = (_Float16*)(ws + 80 * MB);
    _Float16* vT      = (_Float16*)(ws + 96 * MB);
    _Float16* O16     = (_Float16*)(ws + 112 * MB);
    _Float16* G16     = (_Float16*)(ws + 128 * MB);        // 32 MB fp16
    _Float16* Gh      = (_Float16*)(ws + 160 * MB);        // 32 MB fp16

    // ---- P0: casts ----
    cast_f32_f16<<<4096, 256, 0, stream>>>(hs, h16, BT * HIDDEN / 8);
    cast8_f32_f16<<<dim3(512, 8), 256, 0, stream>>>(
        wq, wk, wv, wo, fmq_w1, fmq_w2, fmk_w1, fmk_w2,
        wqkv16, wqkv16 + (1 << 20), wqkv16 + (2 << 20), wo16,
        fmw, fmw + 16384, fmw + 2 * 16384, fmw + 3 * 16384,
        HIDDEN * HIDDEN / 8, DKV * DKV / 8);

    // ---- P1: fused QKV projection (N = 3072), 128x128 tiles, BK=64 ----
    dim3 gqkv(3 * HIDDEN / 128, BT / 128);   // (24, 64) = 1536 blocks
    gemm_nt_f16_h16<<<gqkv, 256, 0, stream>>>(h16, wqkv16, qkvlin, BT, 3 * HIDDEN, HIDDEN);

    // ---- P2: conv + silu for V (transposed out) ----
    conv_silu_T<<<2048, 256, 0, stream>>>(qkvlin + 2 * HIDDEN, 3 * HIDDEN, cv, vT);

    // ---- P3: FUSED conv + feature map for q,k (v3 pipelined B) ----
    dim3 fg(BT / 64, NHEAD, 2);
    convfm<<<fg, 256, 0, stream>>>(qkvlin, 3 * HIDDEN, cq, ck, fmw,
                                   fmq_b1, fmq_b2, fmk_b1, fmk_b2, qf16, kf16);

    // ---- P4-P6: chunked linear attention ----
    dim3 ag(NCH, BATCH * NHEAD);
    ktv_mfma<<<ag, 256, 0, stream>>>(kf16, vT, G16);
    prefix_kernel<<<(16 * 16384) / 256, 256, 0, stream>>>(G16, Gh);
    attn_mfma<<<ag, 256, 0, stream>>>(qf16, kf16, vT, Gh, O16);

    // ---- P7: output projection (undo SCALE_O), BK=64 ----
    dim3 gg(HIDDEN / 128, BT / 128);
    gemm_nt_f16_f32<<<gg, 256, 0, stream>>>(O16, wo16, out, BT, HIDDEN, HIDDEN, 1.0f / SCALE_O);
}